// Round 1
// baseline (323.815 us; speedup 1.0000x reference)
//
#include <hip/hip_runtime.h>
#include <cstdint>

typedef float f32x4 __attribute__((ext_vector_type(4)));
typedef short s16x8 __attribute__((ext_vector_type(8)));

#define APAD 72   // padded row length (bf16 elems): 144 B rows, 16B-aligned, bank-floor

__device__ __forceinline__ unsigned short f2bf(float f) {
  union { float f; uint32_t u; } v; v.f = f;
  uint32_t u = v.u;
  u += 0x7fffu + ((u >> 16) & 1u);
  return (unsigned short)(u >> 16);
}
__device__ __forceinline__ float bf2f(unsigned short h) {
  union { uint32_t u; float f; } v; v.u = ((uint32_t)h) << 16;
  return v.f;
}
__device__ __forceinline__ float sigmoidf_(float x) {
  return 1.0f / (1.0f + __expf(-x));
}
__device__ __forceinline__ f32x4 zero4() {
  f32x4 z = {0.f, 0.f, 0.f, 0.f};
  return z;
}
// async global->LDS, 16 B per lane. LDS dest must be (wave-uniform base + lane*16).
__device__ __forceinline__ void gl_lds16(const void* g, void* l) {
  __builtin_amdgcn_global_load_lds(
      (const __attribute__((address_space(1))) uint32_t*)g,
      (__attribute__((address_space(3))) uint32_t*)l, 16, 0, 0);
}

// ---------------------------------------------------------------------------
// prep: transpose 6 weight matrices [k][n] fp32 -> WT bf16 [m][n][APAD] (W^T)
// ---------------------------------------------------------------------------
__global__ __launch_bounds__(256) void k_prep(
    const float* __restrict__ Wlp, const float* __restrict__ Wrp,
    const float* __restrict__ Wlg, const float* __restrict__ Wrg,
    const float* __restrict__ Wog, const float* __restrict__ Wout,
    unsigned short* __restrict__ wt) {
  const float* srcs[6] = {Wlp, Wrp, Wlg, Wrg, Wog, Wout};
  const int m = blockIdx.x;          // one matrix per block
  const float* W = srcs[m];
  const int t = threadIdx.x;
  for (int e = t; e < 4096; e += 256) {
    const int n = e >> 6, k = e & 63;
    wt[m * (64 * APAD) + n * APAD + k] = f2bf(W[k * 64 + n]);
  }
}

// ---------------------------------------------------------------------------
// k1: x = LN(in); left=(x@Wlp+blp)*mask*sig(x@Wlg+blg); right analog.
//     writes leftT/rightT as bf16 [B][C][L][L]  (channel-major, k contiguous)
// grid: B*L*(L/64) = 8192 blocks, 256 thr. Tile = 64 positions (fixed b,i).
// ---------------------------------------------------------------------------
__global__ __launch_bounds__(256) void k1_proj(
    const float* __restrict__ xin, const float* __restrict__ mask,
    const float* __restrict__ lnw, const float* __restrict__ lnb,
    const float* __restrict__ blp, const float* __restrict__ brp,
    const float* __restrict__ blg, const float* __restrict__ brg,
    const unsigned short* __restrict__ wt,
    unsigned short* __restrict__ leftT, unsigned short* __restrict__ rightT) {
  __shared__ unsigned short WT[4 * 64 * APAD];   // lp,rp,lg,rg transposed
  __shared__ unsigned short A[64 * APAD];        // layernormed x, bf16
  __shared__ unsigned short T[64 * APAD];        // transpose-out buffer
  const int tid = threadIdx.x;
  const int bid = blockIdx.x;
  const int b = bid >> 12;
  const int i = (bid >> 3) & 511;
  const int k0 = (bid & 7) << 6;

  // stage W^T (mats 0..3): 36864 B = 9 * (256 lanes * 16 B)
#pragma unroll
  for (int it = 0; it < 9; ++it) {
    const int off = (it * 256 + tid) * 16;
    gl_lds16((const char*)wt + off, (char*)WT + off);
  }

  // load x rows + layernorm (4 threads per row, 16 ch each)
  const int p = tid >> 2, q = tid & 3;
  const float* xrow = xin + (((size_t)b * 512 + i) * 512 + k0 + p) * 64 + q * 16;
  f32x4 xv[4];
#pragma unroll
  for (int u = 0; u < 4; ++u) xv[u] = ((const f32x4*)xrow)[u];
  float s1 = 0.f, s2 = 0.f;
#pragma unroll
  for (int u = 0; u < 4; ++u)
#pragma unroll
    for (int e = 0; e < 4; ++e) { float t = xv[u][e]; s1 += t; s2 += t * t; }
  s1 += __shfl_xor(s1, 1); s2 += __shfl_xor(s2, 1);
  s1 += __shfl_xor(s1, 2); s2 += __shfl_xor(s2, 2);
  const float mu = s1 * 0.015625f;
  const float rs = rsqrtf(s2 * 0.015625f - mu * mu + 1e-5f);
  {
    uint32_t pk[8];
#pragma unroll
    for (int u = 0; u < 4; ++u) {
      f32x4 wv = ((const f32x4*)(lnw + q * 16))[u];
      f32x4 bv = ((const f32x4*)(lnb + q * 16))[u];
#pragma unroll
      for (int e2 = 0; e2 < 2; ++e2) {
        uint32_t lo = f2bf((xv[u][2 * e2] - mu) * rs * wv[2 * e2] + bv[2 * e2]);
        uint32_t hi = f2bf((xv[u][2 * e2 + 1] - mu) * rs * wv[2 * e2 + 1] + bv[2 * e2 + 1]);
        pk[u * 2 + e2] = lo | (hi << 16);
      }
    }
    uint32_t* a32 = (uint32_t*)&A[p * APAD + q * 16];
#pragma unroll
    for (int u = 0; u < 8; ++u) a32[u] = pk[u];
  }
  const float mval = mask[b * 512 + i];
  __syncthreads();

  // MFMA: [64 pos x 64 k] @ [64 k x 64 n] for 4 matrices
  const int lane = tid & 63, w = tid >> 6;
  const int arow = (w * 16 + (lane & 15)) * APAD + ((lane >> 4) << 3);
  const s16x8 a0 = *(const s16x8*)&A[arow];
  const s16x8 a1 = *(const s16x8*)&A[arow + 32];
  f32x4 acc[4][4];
#pragma unroll
  for (int m = 0; m < 4; ++m)
#pragma unroll
    for (int nf = 0; nf < 4; ++nf) acc[m][nf] = zero4();
#pragma unroll
  for (int m = 0; m < 4; ++m) {
#pragma unroll
    for (int nf = 0; nf < 4; ++nf) {
      const int brow = (m * 64 + nf * 16 + (lane & 15)) * APAD + ((lane >> 4) << 3);
      const s16x8 b0 = *(const s16x8*)&WT[brow];
      const s16x8 b1 = *(const s16x8*)&WT[brow + 32];
      acc[m][nf] = __builtin_amdgcn_mfma_f32_16x16x32_bf16(a0, b0, acc[m][nf], 0, 0, 0);
      acc[m][nf] = __builtin_amdgcn_mfma_f32_16x16x32_bf16(a1, b1, acc[m][nf], 0, 0, 0);
    }
  }

  const int fn = lane & 15;
  const int fr4 = (lane >> 4) << 2;
  const int sn = tid >> 2, sq = tid & 3;

  // ---- LEFT: combine, transpose via LDS, store [b][c][i][k-tile] ----
#pragma unroll
  for (int nf = 0; nf < 4; ++nf) {
    const int n = nf * 16 + fn;
    const float bl = blp[n], bg = blg[n];
    float v0 = (acc[0][nf][0] + bl) * mval * sigmoidf_(acc[2][nf][0] + bg);
    float v1 = (acc[0][nf][1] + bl) * mval * sigmoidf_(acc[2][nf][1] + bg);
    float v2 = (acc[0][nf][2] + bl) * mval * sigmoidf_(acc[2][nf][2] + bg);
    float v3 = (acc[0][nf][3] + bl) * mval * sigmoidf_(acc[2][nf][3] + bg);
    const int prow = w * 16 + fr4;
    *(uint32_t*)&T[n * APAD + prow] = (uint32_t)f2bf(v0) | ((uint32_t)f2bf(v1) << 16);
    *(uint32_t*)&T[n * APAD + prow + 2] = (uint32_t)f2bf(v2) | ((uint32_t)f2bf(v3) << 16);
  }
  __syncthreads();
  {
    const uint32_t* src = (const uint32_t*)&T[sn * APAD + sq * 16];
    uint32_t* d32 = (uint32_t*)(leftT + ((((size_t)b * 64 + sn) * 512 + i) * 512 + k0 + sq * 16));
#pragma unroll
    for (int u = 0; u < 8; ++u) d32[u] = src[u];
  }
  __syncthreads();
  // ---- RIGHT ----
#pragma unroll
  for (int nf = 0; nf < 4; ++nf) {
    const int n = nf * 16 + fn;
    const float bl = brp[n], bg = brg[n];
    float v0 = (acc[1][nf][0] + bl) * mval * sigmoidf_(acc[3][nf][0] + bg);
    float v1 = (acc[1][nf][1] + bl) * mval * sigmoidf_(acc[3][nf][1] + bg);
    float v2 = (acc[1][nf][2] + bl) * mval * sigmoidf_(acc[3][nf][2] + bg);
    float v3 = (acc[1][nf][3] + bl) * mval * sigmoidf_(acc[3][nf][3] + bg);
    const int prow = w * 16 + fr4;
    *(uint32_t*)&T[n * APAD + prow] = (uint32_t)f2bf(v0) | ((uint32_t)f2bf(v1) << 16);
    *(uint32_t*)&T[n * APAD + prow + 2] = (uint32_t)f2bf(v2) | ((uint32_t)f2bf(v3) << 16);
  }
  __syncthreads();
  {
    const uint32_t* src = (const uint32_t*)&T[sn * APAD + sq * 16];
    uint32_t* d32 = (uint32_t*)(rightT + ((((size_t)b * 64 + sn) * 512 + i) * 512 + k0 + sq * 16));
#pragma unroll
    for (int u = 0; u < 8; ++u) d32[u] = src[u];
  }
}

// ---------------------------------------------------------------------------
// k2: triT[b,c,i,j] = sum_k leftT[b,c,i,k] * rightT[b,c,j,k]
// 128 planes x 16 tiles of 128x128, BK=64 double-buffered global_load_lds.
// grid 2048, 256 thr (4 waves, each computes 64x64).
// ---------------------------------------------------------------------------
__global__ __launch_bounds__(256) void k2_gemm(
    const unsigned short* __restrict__ leftT,
    const unsigned short* __restrict__ rightT,
    unsigned short* __restrict__ triT) {
  __shared__ unsigned short Ab[2][128 * 64];
  __shared__ unsigned short Bb[2][128 * 64];
  const int tid = threadIdx.x, lane = tid & 63, w = tid >> 6;
  const int bid = blockIdx.x;
  // XCD swizzle: each XCD gets 16 consecutive planes (plane data L2-resident)
  const int sw = ((bid & 7) << 8) | (bid >> 3);
  const int plane = sw >> 4, tile = sw & 15;
  const size_t pb = (size_t)plane * 262144;
  const int i0 = (tile >> 2) << 7, j0 = (tile & 3) << 7;
  const int srow = lane >> 3;            // row-in-chunk
  const int sk = (lane & 7) << 3;        // k-elems within row (8 elems = 16 B)

  f32x4 acc[4][4];
#pragma unroll
  for (int mf = 0; mf < 4; ++mf)
#pragma unroll
    for (int nf = 0; nf < 4; ++nf) acc[mf][nf] = zero4();
  const int wr = (w >> 1) << 6, wc = (w & 1) << 6;

  auto stage = [&](int buf, int kt) {
    const int kk = kt << 6;
#pragma unroll
    for (int it = 0; it < 4; ++it) {
      const int ch = it * 4 + w;                 // 16 chunks of 1 KB
      const int row = (ch << 3) + srow;
      gl_lds16(leftT + pb + (size_t)(i0 + row) * 512 + kk + sk,
               (char*)&Ab[buf][0] + ch * 1024 + lane * 16);
      gl_lds16(rightT + pb + (size_t)(j0 + row) * 512 + kk + sk,
               (char*)&Bb[buf][0] + ch * 1024 + lane * 16);
    }
  };

  stage(0, 0);
  for (int kt = 0; kt < 8; ++kt) {
    __syncthreads();                       // drains vmcnt: buf[kt&1] ready
    if (kt < 7) stage((kt & 1) ^ 1, kt + 1);
    const unsigned short* Ac = &Ab[kt & 1][0];
    const unsigned short* Bc = &Bb[kt & 1][0];
#pragma unroll
    for (int ks = 0; ks < 2; ++ks) {
      const int ko = ((lane >> 4) << 3) + (ks << 5);
      s16x8 af[4], bfr[4];
#pragma unroll
      for (int mf = 0; mf < 4; ++mf)
        af[mf] = *(const s16x8*)&Ac[(wr + mf * 16 + (lane & 15)) * 64 + ko];
#pragma unroll
      for (int nf = 0; nf < 4; ++nf)
        bfr[nf] = *(const s16x8*)&Bc[(wc + nf * 16 + (lane & 15)) * 64 + ko];
#pragma unroll
      for (int mf = 0; mf < 4; ++mf)
#pragma unroll
        for (int nf = 0; nf < 4; ++nf)
          acc[mf][nf] = __builtin_amdgcn_mfma_f32_16x16x32_bf16(af[mf], bfr[nf], acc[mf][nf], 0, 0, 0);
    }
  }
  __syncthreads();
  // repack 128x128 bf16 into LDS (reuse Ab), then coalesced store
  unsigned short* Tt = &Ab[0][0];
#pragma unroll
  for (int mf = 0; mf < 4; ++mf)
#pragma unroll
    for (int nf = 0; nf < 4; ++nf) {
      const int col = wc + nf * 16 + (lane & 15);
#pragma unroll
      for (int r = 0; r < 4; ++r) {
        const int row = wr + mf * 16 + ((lane >> 4) << 2) + r;
        Tt[row * 128 + col] = f2bf(acc[mf][nf][r]);
      }
    }
  __syncthreads();
  {
    const int row = tid >> 1, half = (tid & 1) << 6;
    const uint32_t* src = (const uint32_t*)&Tt[row * 128 + half];
    uint32_t* dst = (uint32_t*)(triT + pb + (size_t)(i0 + row) * 512 + j0 + half);
#pragma unroll
    for (int u = 0; u < 32; ++u) dst[u] = src[u];
  }
}

// ---------------------------------------------------------------------------
// k3: y = LN_out(tri) * sigmoid(LN_in(resid)@Wog+bog); out = y@Wout+bout+resid
// grid B*L*(L/64) = 8192 blocks; tile = 64 j-positions of row (b,i).
// ---------------------------------------------------------------------------
__global__ __launch_bounds__(256) void k3_out(
    const unsigned short* __restrict__ triT,
    const float* __restrict__ resid,
    const float* __restrict__ lnw1, const float* __restrict__ lnb1,
    const float* __restrict__ bog,
    const float* __restrict__ lnw2, const float* __restrict__ lnb2,
    const float* __restrict__ bout,
    const unsigned short* __restrict__ wt,
    float* __restrict__ outp) {
  __shared__ unsigned short WT[2 * 64 * APAD];   // og^T, out^T
  __shared__ unsigned short Y[64 * APAD];        // tri tile [j][c] -> later y bf16
  __shared__ unsigned short X[64 * APAD];        // LN_in(resid) bf16
  __shared__ unsigned short OG[64 * APAD];       // sigmoid gate bf16
  const int tid = threadIdx.x, lane = tid & 63, w = tid >> 6;
  const int bid = blockIdx.x;
  const int b = bid >> 12;
  const int i = (bid >> 3) & 511;
  const int j0 = (bid & 7) << 6;

  // stage W^T mats 4..5 (18432 B)
  const char* wsrc = (const char*)(wt + 4 * 64 * APAD);
#pragma unroll
  for (int it = 0; it < 5; ++it) {
    const int off = (it * 256 + tid) * 16;
    if (off < 18432) gl_lds16(wsrc + off, (char*)WT + off);
  }

  const int j = tid >> 2, q = tid & 3;
  // tri tile load + transpose scatter into Y[j][c]
  {
    const int c = tid >> 2;
    const size_t srow = ((size_t)(b * 64 + c) * 512 + i) * 512 + j0 + q * 16;
    union { uint32_t u32[8]; unsigned short s[16]; } uu;
    const uint32_t* s32 = (const uint32_t*)(triT + srow);
#pragma unroll
    for (int u = 0; u < 8; ++u) uu.u32[u] = s32[u];
#pragma unroll
    for (int s = 0; s < 16; ++s) Y[(q * 16 + s) * APAD + c] = uu.s[s];
  }
  // residual LN_in -> X (A-tile for og matmul)
  {
    const float* rrow = resid + (((size_t)b * 512 + i) * 512 + j0 + j) * 64 + q * 16;
    f32x4 rv[4];
#pragma unroll
    for (int u = 0; u < 4; ++u) rv[u] = ((const f32x4*)rrow)[u];
    float s1 = 0.f, s2 = 0.f;
#pragma unroll
    for (int u = 0; u < 4; ++u)
#pragma unroll
      for (int e = 0; e < 4; ++e) { float t = rv[u][e]; s1 += t; s2 += t * t; }
    s1 += __shfl_xor(s1, 1); s2 += __shfl_xor(s2, 1);
    s1 += __shfl_xor(s1, 2); s2 += __shfl_xor(s2, 2);
    const float mu = s1 * 0.015625f;
    const float rs = rsqrtf(s2 * 0.015625f - mu * mu + 1e-5f);
    uint32_t pk[8];
#pragma unroll
    for (int u = 0; u < 4; ++u) {
      f32x4 wv = ((const f32x4*)(lnw1 + q * 16))[u];
      f32x4 bv = ((const f32x4*)(lnb1 + q * 16))[u];
#pragma unroll
      for (int e2 = 0; e2 < 2; ++e2) {
        uint32_t lo = f2bf((rv[u][2 * e2] - mu) * rs * wv[2 * e2] + bv[2 * e2]);
        uint32_t hi = f2bf((rv[u][2 * e2 + 1] - mu) * rs * wv[2 * e2 + 1] + bv[2 * e2 + 1]);
        pk[u * 2 + e2] = lo | (hi << 16);
      }
    }
    uint32_t* x32 = (uint32_t*)&X[j * APAD + q * 16];
#pragma unroll
    for (int u = 0; u < 8; ++u) x32[u] = pk[u];
  }
  __syncthreads();

  // tri LN stats (per j-row; kept in regs across phases)
  float yv[16];
  {
    union { uint32_t u32[8]; unsigned short s[16]; } uy;
    const uint32_t* y32 = (const uint32_t*)&Y[j * APAD + q * 16];
#pragma unroll
    for (int u = 0; u < 8; ++u) uy.u32[u] = y32[u];
#pragma unroll
    for (int s = 0; s < 16; ++s) yv[s] = bf2f(uy.s[s]);
  }
  float t1 = 0.f, t2 = 0.f;
#pragma unroll
  for (int s = 0; s < 16; ++s) { t1 += yv[s]; t2 += yv[s] * yv[s]; }
  t1 += __shfl_xor(t1, 1); t2 += __shfl_xor(t2, 1);
  t1 += __shfl_xor(t1, 2); t2 += __shfl_xor(t2, 2);
  const float mu2 = t1 * 0.015625f;
  const float rs2 = rsqrtf(t2 * 0.015625f - mu2 * mu2 + 1e-5f);

  // og = sigmoid(X @ Wog + bog)
  const int arow = (w * 16 + (lane & 15)) * APAD + ((lane >> 4) << 3);
  {
    const s16x8 a0 = *(const s16x8*)&X[arow];
    const s16x8 a1 = *(const s16x8*)&X[arow + 32];
    f32x4 aog[4];
#pragma unroll
    for (int nf = 0; nf < 4; ++nf) aog[nf] = zero4();
#pragma unroll
    for (int nf = 0; nf < 4; ++nf) {
      const int brow = (nf * 16 + (lane & 15)) * APAD + ((lane >> 4) << 3);
      const s16x8 b0 = *(const s16x8*)&WT[brow];
      const s16x8 b1 = *(const s16x8*)&WT[brow + 32];
      aog[nf] = __builtin_amdgcn_mfma_f32_16x16x32_bf16(a0, b0, aog[nf], 0, 0, 0);
      aog[nf] = __builtin_amdgcn_mfma_f32_16x16x32_bf16(a1, b1, aog[nf], 0, 0, 0);
    }
#pragma unroll
    for (int nf = 0; nf < 4; ++nf) {
      const int n = nf * 16 + (lane & 15);
      const float bb = bog[n];
#pragma unroll
      for (int r = 0; r < 4; ++r) {
        const int prow = w * 16 + ((lane >> 4) << 2) + r;
        OG[prow * APAD + n] = f2bf(sigmoidf_(aog[nf][r] + bb));
      }
    }
  }
  __syncthreads();

  // y = LN_out(tri) * og  -> Y (bf16)
  {
    union { uint32_t u32[8]; unsigned short s[16]; } og_;
    const uint32_t* o32 = (const uint32_t*)&OG[j * APAD + q * 16];
#pragma unroll
    for (int u = 0; u < 8; ++u) og_.u32[u] = o32[u];
    uint32_t pk[8];
#pragma unroll
    for (int u = 0; u < 4; ++u) {
      f32x4 wv = ((const f32x4*)(lnw2 + q * 16))[u];
      f32x4 bv = ((const f32x4*)(lnb2 + q * 16))[u];
#pragma unroll
      for (int e2 = 0; e2 < 2; ++e2) {
        const int s0 = u * 4 + 2 * e2;
        float y0 = ((yv[s0] - mu2) * rs2 * wv[2 * e2] + bv[2 * e2]) * bf2f(og_.s[s0]);
        float y1 = ((yv[s0 + 1] - mu2) * rs2 * wv[2 * e2 + 1] + bv[2 * e2 + 1]) * bf2f(og_.s[s0 + 1]);
        pk[u * 2 + e2] = (uint32_t)f2bf(y0) | ((uint32_t)f2bf(y1) << 16);
      }
    }
    uint32_t* y32 = (uint32_t*)&Y[j * APAD + q * 16];
#pragma unroll
    for (int u = 0; u < 8; ++u) y32[u] = pk[u];
  }
  __syncthreads();

  // out = Y @ Wout + bout + resid
  {
    const s16x8 a0 = *(const s16x8*)&Y[arow];
    const s16x8 a1 = *(const s16x8*)&Y[arow + 32];
    f32x4 ao[4];
#pragma unroll
    for (int nf = 0; nf < 4; ++nf) ao[nf] = zero4();
#pragma unroll
    for (int nf = 0; nf < 4; ++nf) {
      const int brow = 64 * APAD + (nf * 16 + (lane & 15)) * APAD + ((lane >> 4) << 3);
      const s16x8 b0 = *(const s16x8*)&WT[brow];
      const s16x8 b1 = *(const s16x8*)&WT[brow + 32];
      ao[nf] = __builtin_amdgcn_mfma_f32_16x16x32_bf16(a0, b0, ao[nf], 0, 0, 0);
      ao[nf] = __builtin_amdgcn_mfma_f32_16x16x32_bf16(a1, b1, ao[nf], 0, 0, 0);
    }
#pragma unroll
    for (int nf = 0; nf < 4; ++nf) {
      const int n = nf * 16 + (lane & 15);
      const float bo = bout[n];
#pragma unroll
      for (int r = 0; r < 4; ++r) {
        const int pj = w * 16 + ((lane >> 4) << 2) + r;
        const size_t o = (((size_t)b * 512 + i) * 512 + j0 + pj) * 64 + n;
        outp[o] = ao[nf][r] + bo + resid[o];
      }
    }
  }
}

// ---------------------------------------------------------------------------
extern "C" void kernel_launch(void* const* d_in, const int* in_sizes, int n_in,
                              void* d_out, int out_size, void* d_ws, size_t ws_size,
                              hipStream_t stream) {
  const float* x     = (const float*)d_in[0];
  const float* mask  = (const float*)d_in[1];
  const float* lnw1  = (const float*)d_in[2];
  const float* lnb1  = (const float*)d_in[3];
  const float* Wlp   = (const float*)d_in[4];
  const float* blp   = (const float*)d_in[5];
  const float* Wrp   = (const float*)d_in[6];
  const float* brp   = (const float*)d_in[7];
  const float* Wlg   = (const float*)d_in[8];
  const float* blg   = (const float*)d_in[9];
  const float* Wrg   = (const float*)d_in[10];
  const float* brg   = (const float*)d_in[11];
  const float* Wog   = (const float*)d_in[12];
  const float* bog   = (const float*)d_in[13];
  const float* lnw2  = (const float*)d_in[14];
  const float* lnb2  = (const float*)d_in[15];
  const float* Wout  = (const float*)d_in[16];
  const float* bout  = (const float*)d_in[17];

  // ws layout (bf16 elems): leftT | rightT | triT  each [2][64][512][512], then WT
  unsigned short* leftT  = (unsigned short*)d_ws;
  unsigned short* rightT = leftT + (size_t)33554432;
  unsigned short* triT   = rightT + (size_t)33554432;
  unsigned short* wt     = triT + (size_t)33554432;   // 6*64*72 bf16

  k_prep<<<6, 256, 0, stream>>>(Wlp, Wrp, Wlg, Wrg, Wog, Wout, wt);
  k1_proj<<<8192, 256, 0, stream>>>(x, mask, lnw1, lnb1, blp, brp, blg, brg,
                                    wt, leftT, rightT);
  k2_gemm<<<2048, 256, 0, stream>>>(leftT, rightT, triT);
  k3_out<<<8192, 256, 0, stream>>>(triT, x, lnw1, lnb1, bog, lnw2, lnb2, bout,
                                   wt, (float*)d_out);
}